// Round 5
// baseline (427.835 us; speedup 1.0000x reference)
//
#include <hip/hip_runtime.h>

#define NCH 6
#define NX 32
#define PLANE 1024                  // 32x32 cells per x-plane
#define NCELL (NX * PLANE)
#define STEP_STRIDE (NCH * NCELL)   // floats per history slice
#define NTHREADS 256                // 2 planes x 4 rows x 32 z = 256 own cells
#define NBLOCKS 128                 // 16 x-pairs x 8 y-stripes
#define RB 2                        // ring slots; (slot, sign-parity) = epoch mod 4
#define RING_WORDS ((size_t)RB * 3 * NCELL)
#define F_DONE 0

// R4: TEMPORAL BATCHING k=2. Geometry history: per-step handshake cost is
// ~2us across 64/256/1024-thread blocks (R3/R10/R2: 190/181/248us) -> the
// stepper is bound by the COUNT of sequential ring round-trips, not their
// shape. This round halves the count: one handshake per 2 CA steps.
//   block = 2 x-planes x 4 y-rows (256 thr). Per handshake h (epoch=h):
//   poll phi_{2h} on radius-2 halo (<=5 cells x 3 u64/thread, batched),
//   step1: phi_{2h+1} on radius-1 box (3 cells/thread, dregh in 108 VGPR),
//   step2: phi_{2h+2} on own cell, publish ONLY phi_{2h+2}.
// Protocol (slot=h&1, parity=(h>>1)&1 in sign bits, poison 0xAA tag-fails,
// fire-and-forget stores, flag-abort) is byte-identical semantics to
// R9/R10-proven; mutual-partner skew<=1 handshake, no-deadlock argument
// carries with t->h. Redundant halo compute rides the 93%-idle VALU.
// Predict stepper 110-140us, WRITE 135->~100MB, absmax 0.

typedef unsigned long long u64;

__device__ __forceinline__ u64 ld64(const u64* p) {
    return __hip_atomic_load(p, __ATOMIC_RELAXED, __HIP_MEMORY_SCOPE_SYSTEM);
}
__device__ __forceinline__ void st64(u64* p, u64 v) {
    __hip_atomic_store(p, v, __ATOMIC_RELAXED, __HIP_MEMORY_SCOPE_SYSTEM);
}
__device__ __forceinline__ int ldi(const int* p) {
    return __hip_atomic_load(p, __ATOMIC_RELAXED, __HIP_MEMORY_SCOPE_SYSTEM);
}
__device__ __forceinline__ void sti(int* p, int v) {
    __hip_atomic_store(p, v, __ATOMIC_RELAXED, __HIP_MEMORY_SCOPE_SYSTEM);
}
__device__ __forceinline__ u64 pack2p(float a, float b, unsigned P) {
    const u64 w = ((u64)__float_as_uint(b) << 32) | __float_as_uint(a);
    return P ? (w | 0x8000000080000000ULL) : w;
}
__device__ __forceinline__ bool tagok(u64 w, unsigned P) {
    return (((unsigned)(w >> 63)) == P) & ((((unsigned)w) >> 31) == P);
}

__global__ void __launch_bounds__(NTHREADS, 1)
BEMNA_V7_2_PhaseSpace_44117904064519_kernel(
    const float* __restrict__ D,
    const int* __restrict__ sx_p, const int* __restrict__ sy_p,
    const int* __restrict__ sz_p, const int* __restrict__ ex_p,
    const int* __restrict__ ey_p, const int* __restrict__ ez_p,
    const int* __restrict__ maxit_p,
    float* __restrict__ out,
    u64* __restrict__ ring,
    int* __restrict__ flags)
{
    // phiT: phi_{2h} on 6 planes (x0-2..x0+3) x 8 rows (y0-2..y1+2) x 32 z,
    //       3 u64 streams (ch pairs). phi1: phi_{2h+1} on 4 planes x 6 rows.
    __shared__ u64 phiTu[3 * 6 * 8 * 32];      // stream stride 1536
    __shared__ u64 phi1u[3 * 4 * 6 * 32];      // stream stride 768
    __shared__ int lds_dn;
    volatile int* vdn = &lds_dn;

    const int tid = (int)threadIdx.x;
    const int bx  = (int)blockIdx.x;
    const int x0  = (bx >> 3) << 1;            // x-pair base plane
    const int y0  = (bx & 7) << 2;             // y-stripe base row
    const int tr  = tid >> 5;                  // row-unit 0..7
    const int z   = tid & 31;
    const int pl  = tr >> 2;                   // 0..1 own plane
    const int rr  = tr & 3;                    // 0..3 own row
    const int xg0 = x0 + pl, yg0 = y0 + rr;
    const int cell = (xg0 << 10) + (yg0 << 5) + z;

    const int sx = *sx_p, sy = *sy_p, sz = *sz_p;
    const int ex = *ex_p, ey = *ey_p, ez = *ez_p;
    const int maxit = *maxit_p;
    const bool is_seed   = (cell == ((sx << 10) | (sy << 5) | sz));
    const bool is_target = (cell == ((ex << 10) | (ey << 5) | ez));

    // ---- own-cell step-2 coefficients (identical to k=1 dreg) ----
    const int  nbg[NCH] = { cell - PLANE, cell + PLANE, cell - 32, cell + 32, cell - 1, cell + 1 };
    const bool okো[NCH] = { xg0 >= 1, xg0 <= 30, yg0 >= 1, yg0 <= 30, z >= 1, z <= 30 };
    float dreg2[NCH][NCH];
#pragma unroll
    for (int o = 0; o < NCH; ++o)
#pragma unroll
        for (int i = 0; i < NCH; ++i)
            dreg2[o][i] = okো[o] ? D[(size_t)(o * NCH + i) * NCELL + nbg[o]] + 0.95f : 0.0f;

    // ---- step-1 cell assignments: 24 (plane,row) pairs, 3 per row-unit ----
    // S1 box: px 0..3 <-> x0-1..x0+2, ry 0..5 <-> y0-1..y1+1
    float dregh[3][NCH][NCH];
    int nbm[3][6], wof[3];
#pragma unroll
    for (int m = 0; m < 3; ++m) {
        const int q1 = tr + 8 * m;             // 0..23, unique per (tr,m)
        const int px = q1 / 6, ry = q1 % 6;
        const int xs = x0 + px - 1, ys = y0 + ry - 1;
        const bool cv = (xs >= 0) && (xs <= 31) && (ys >= 0) && (ys <= 31);
        const int c1 = xs * PLANE + ys * 32 + z;
        const int nb1[6] = { c1 - PLANE, c1 + PLANE, c1 - 32, c1 + 32, c1 - 1, c1 + 1 };
        const bool okh[6] = { cv && xs >= 1, cv && xs <= 30, cv && ys >= 1,
                              cv && ys <= 30, cv && z >= 1, cv && z <= 30 };
#pragma unroll
        for (int o = 0; o < 6; ++o)
#pragma unroll
            for (int i = 0; i < 6; ++i)
                dregh[m][o][i] = okh[o] ? D[(size_t)(o * 6 + i) * NCELL + nb1[o]] + 0.95f : 0.0f;
        const int pT = px + 1, rT = ry + 1;    // phiT coords
        nbm[m][0] = ((pT - 1) * 8 + rT) * 32 + z;
        nbm[m][1] = ((pT + 1) * 8 + rT) * 32 + z;
        nbm[m][2] = (pT * 8 + (rT - 1)) * 32 + z;
        nbm[m][3] = (pT * 8 + (rT + 1)) * 32 + z;
        nbm[m][4] = (pT * 8 + rT) * 32 + z - 1;   // z flat -1: masked at z=0
        nbm[m][5] = (pT * 8 + rT) * 32 + z + 1;   // z flat +1: masked at z=31
        wof[m] = px * 192 + ry * 32 + z;          // phi1 slot (stride: plane 192, row 32)
    }

    // ---- poll assignments: 1152 halo cells (36 row-units), <=5 per thread ----
    // segs (row-units): pT=0 rT1..6 | pT=1 rT0..7 | pT=4 rT0..7 | pT=5 rT1..6
    //                 | pT=2 rT{0,1,6,7} | pT=3 rT{0,1,6,7}
    int cg[5], po[5];
    unsigned vld = 0;
#pragma unroll
    for (int j = 0; j < 5; ++j) {
        const int q = tr + 8 * j;
        cg[j] = 0; po[j] = 0;
        if (q < 36) {
            int pT, rT;
            if      (q <  6) { pT = 0; rT = q + 1; }
            else if (q < 14) { pT = 1; rT = q - 6; }
            else if (q < 22) { pT = 4; rT = q - 14; }
            else if (q < 28) { pT = 5; rT = q - 21; }
            else if (q < 32) { const int u = q - 28; pT = 2; rT = (u < 2) ? u : u + 4; }
            else             { const int u = q - 32; pT = 3; rT = (u < 2) ? u : u + 4; }
            const int xg = x0 + pT - 2, yg = y0 + rT - 2;
            if (xg >= 0 && xg <= 31 && yg >= 0 && yg <= 31) {
                vld |= 1u << j;
                cg[j] = (xg << 10) + (yg << 5) + z;
                po[j] = (pT * 8 + rT) * 32 + z;
            }
        }
    }
    const int ownT = ((pl + 2) * 8 + (rr + 2)) * 32 + z;   // own slot in phiT
    const int owno = (pl + 1) * 192 + (rr + 1) * 32 + z;   // own slot in phi1
    int nb2[6];
    nb2[0] = pl * 192 + (rr + 1) * 32 + z;
    nb2[1] = (pl + 2) * 192 + (rr + 1) * 32 + z;
    nb2[2] = (pl + 1) * 192 + rr * 32 + z;
    nb2[3] = (pl + 1) * 192 + (rr + 2) * 32 + z;
    nb2[4] = (pl + 1) * 192 + (rr + 1) * 32 + z - 1;
    nb2[5] = (pl + 1) * 192 + (rr + 1) * 32 + z + 1;

    // zero phiT once: never-written slots (out-of-grid, unused corners) stay 0
    for (int k2 = tid; k2 < 3 * 1536; k2 += NTHREADS) phiTu[k2] = 0;

    // ---- init: epoch 0 (slot 0, parity 0), hist slice 0, cur ----
    const float iv = is_seed ? 1.0f : 0.0f;
    u64 cur0, cur1, cur2;
    {
        const u64 pk = pack2p(iv, iv, 0);
        cur0 = pk; cur1 = pk; cur2 = pk;
        st64(&ring[0 * NCELL + cell], pk);
        st64(&ring[1 * NCELL + cell], pk);
        st64(&ring[2 * NCELL + cell], pk);
        float* outp = out + cell;
#pragma unroll
        for (int o = 0; o < NCH; ++o) outp[o * NCELL] = iv;
    }
    if (tid == 0) lds_dn = -1;
    __syncthreads();

    int tripped = 0;
    for (int h = 0; 2 * h + 1 <= maxit - 1; ++h) {
        const int s1 = 2 * h + 1;
        const bool do2 = (s1 + 1 <= maxit - 1);
        const u64* r0 = ring + (size_t)(h & 1) * 3 * NCELL;
        const u64* r1 = r0 + NCELL;
        const u64* r2 = r1 + NCELL;
        const unsigned P = (unsigned)((h >> 1) & 1);

        u64 w[5][3] = {};
        for (;;) {
            // batched loads -> one waitcnt, one L3 RT per round
#pragma unroll
            for (int j = 0; j < 5; ++j) if (vld & (1u << j)) {
                w[j][0] = ld64(r0 + cg[j]);
                w[j][1] = ld64(r1 + cg[j]);
                w[j][2] = ld64(r2 + cg[j]);
            }
            if ((tid & 63) == 0) {             // lane0/wave: done-flag duty
                const int dn = ldi(&flags[F_DONE]);
                if (dn >= 0) *vdn = dn;
            }
            bool okr = true;
#pragma unroll
            for (int j = 0; j < 5; ++j) if (vld & (1u << j))
                okr = okr & tagok(w[j][0], P) & tagok(w[j][1], P) & tagok(w[j][2], P);
            const int d = *vdn;
            if (d >= 0 && s1 > d) break;       // abort: data moot
            if (__ballot(okr) == ~0ull) break;
            __builtin_amdgcn_s_sleep(1);
        }
        // stage polled halo (parity-stripped) + own cell into phiT
#pragma unroll
        for (int j = 0; j < 5; ++j) if (vld & (1u << j)) {
            phiTu[0 * 1536 + po[j]] = w[j][0] & 0x7fffffff7fffffffULL;
            phiTu[1 * 1536 + po[j]] = w[j][1] & 0x7fffffff7fffffffULL;
            phiTu[2 * 1536 + po[j]] = w[j][2] & 0x7fffffff7fffffffULL;
        }
        phiTu[0 * 1536 + ownT] = cur0 & 0x7fffffff7fffffffULL;
        phiTu[1 * 1536 + ownT] = cur1 & 0x7fffffff7fffffffULL;
        phiTu[2 * 1536 + ownT] = cur2 & 0x7fffffff7fffffffULL;
        __syncthreads();                       // (A) phiT settled block-wide
        { const int d = *vdn; if (d >= 0 && s1 > d) break; }  // uniform abort

        // ---- step 1: phi_{s1} on the radius-1 box, 3 cells/thread ----
#pragma unroll
        for (int m = 0; m < 3; ++m) {
            float a[6] = {0.f, 0.f, 0.f, 0.f, 0.f, 0.f};
#pragma unroll
            for (int k = 0; k < 3; ++k) {
                const int kb = k * 1536;
#pragma unroll
                for (int o = 0; o < 6; ++o) {
                    const u64 wv = phiTu[kb + nbm[m][o]];
                    const float f0 = __uint_as_float((unsigned)wv);
                    const float f1 = __uint_as_float((unsigned)(wv >> 32));
                    a[o] = fmaf(dregh[m][o][2 * k], f0,
                           fmaf(dregh[m][o][2 * k + 1], f1, a[o]));
                }
            }
#pragma unroll
            for (int o = 0; o < 6; ++o) a[o] = fminf(fmaxf(a[o], 0.f), 1.f);
            phi1u[0 * 768 + wof[m]] = pack2p(a[0], a[1], 0);
            phi1u[1 * 768 + wof[m]] = pack2p(a[2], a[3], 0);
            phi1u[2 * 768 + wof[m]] = pack2p(a[4], a[5], 0);
        }
        __syncthreads();                       // (B) phi1 settled block-wide

        // ---- own phi_{s1}: trip + history data ----
        const u64 h0 = phi1u[0 * 768 + owno];
        const u64 h1 = phi1u[1 * 768 + owno];
        const u64 h2 = phi1u[2 * 768 + owno];
        float p1v[6];
        p1v[0] = __uint_as_float((unsigned)h0); p1v[1] = __uint_as_float((unsigned)(h0 >> 32));
        p1v[2] = __uint_as_float((unsigned)h1); p1v[3] = __uint_as_float((unsigned)(h1 >> 32));
        p1v[4] = __uint_as_float((unsigned)h2); p1v[5] = __uint_as_float((unsigned)(h2 >> 32));
        if (is_target && !tripped) {
            if (p1v[0] + p1v[1] + p1v[2] + p1v[3] + p1v[4] + p1v[5] > 0.01f) {
                sti(&flags[F_DONE], s1);
                tripped = 1;
            }
        }

        // ---- step 2: phi_{s1+1} on own cell; publish ----
        float v[6] = {0.f, 0.f, 0.f, 0.f, 0.f, 0.f};
        if (do2) {
#pragma unroll
            for (int k = 0; k < 3; ++k) {
                const int kb = k * 768;
#pragma unroll
                for (int o = 0; o < 6; ++o) {
                    const u64 wv = phi1u[kb + nb2[o]];
                    const float f0 = __uint_as_float((unsigned)wv);
                    const float f1 = __uint_as_float((unsigned)(wv >> 32));
                    v[o] = fmaf(dreg2[o][2 * k], f0,
                           fmaf(dreg2[o][2 * k + 1], f1, v[o]));
                }
            }
#pragma unroll
            for (int o = 0; o < 6; ++o) v[o] = fminf(fmaxf(v[o], 0.f), 1.f);
            if (is_target && !tripped) {
                if (v[0] + v[1] + v[2] + v[3] + v[4] + v[5] > 0.01f) {
                    sti(&flags[F_DONE], s1 + 1);
                    tripped = 1;
                }
            }
            const unsigned P1 = (unsigned)(((h + 1) >> 1) & 1);
            u64* w0 = ring + (size_t)((h + 1) & 1) * 3 * NCELL;
            st64(w0 + 0 * NCELL + cell, pack2p(v[0], v[1], P1));
            st64(w0 + 1 * NCELL + cell, pack2p(v[2], v[3], P1));
            st64(w0 + 2 * NCELL + cell, pack2p(v[4], v[5], P1));
            cur0 = pack2p(v[0], v[1], 0);
            cur1 = pack2p(v[2], v[3], 0);
            cur2 = pack2p(v[4], v[5], 0);
        }

        // history slices last: HBM acks overlap the next poll
        {
            float* op1 = out + (size_t)s1 * STEP_STRIDE + cell;
#pragma unroll
            for (int o = 0; o < NCH; ++o) op1[o * NCELL] = p1v[o];
        }
        if (do2) {
            float* op2 = out + (size_t)(s1 + 1) * STEP_STRIDE + cell;
#pragma unroll
            for (int o = 0; o < NCH; ++o) op2[o * NCELL] = v[o];
        }
    }
}

// Read-once/write-many fill (unchanged): copies frozen slice tf to all later
// slices, overwriting any stepper overshoot. Pure write-bound ~27us.
__global__ void fill_kernel(const int* __restrict__ flags,
                            float4* __restrict__ out,
                            int total4)
{
    const int s4 = STEP_STRIDE / 4;
    const int maxit = total4 / s4;
    const int ds = flags[F_DONE];
    const int tf = (ds >= 1 && ds <= maxit - 1) ? ds : maxit - 1;
    const int idx = (int)blockIdx.x * (int)blockDim.x + (int)threadIdx.x;
    const float4 v = out[(size_t)tf * s4 + idx];
    for (int t = tf + 1; t < maxit; ++t)
        out[(size_t)t * s4 + idx] = v;
}

extern "C" void kernel_launch(void* const* d_in, const int* in_sizes, int n_in,
                              void* d_out, int out_size, void* d_ws, size_t ws_size,
                              hipStream_t stream)
{
    const float* D   = (const float*)d_in[0];
    const int* sx    = (const int*)d_in[1];
    const int* sy    = (const int*)d_in[2];
    const int* sz    = (const int*)d_in[3];
    const int* ex    = (const int*)d_in[4];
    const int* ey    = (const int*)d_in[5];
    const int* ez    = (const int*)d_in[6];
    const int* maxit = (const int*)d_in[7];
    float* out = (float*)d_out;

    u64* ring  = (u64*)d_ws;                   // 2 x 3 x 32768 x 8B = 1.6 MB
    int* flags = (int*)(ring + RING_WORDS);

    BEMNA_V7_2_PhaseSpace_44117904064519_kernel<<<dim3(NBLOCKS), dim3(NTHREADS), 0, stream>>>(
        D, sx, sy, sz, ex, ey, ez, maxit, out, ring, flags);

    const int total4 = out_size / 4;
    fill_kernel<<<dim3((STEP_STRIDE / 4) / 256), dim3(256), 0, stream>>>(
        flags, (float4*)out, total4);
}

// Round 8
// 412.237 us; speedup vs baseline: 1.0378x; 1.0378x over previous
//
#include <hip/hip_runtime.h>

#define NCH 6
#define NX 32
#define PLANE 1024                  // 32x32 cells per x-plane
#define NCELL (NX * PLANE)
#define STEP_STRIDE (NCH * NCELL)   // floats per history slice
#define NTHREADS 256                // one y-stripe (8 rows x 32 z) of a plane
#define NBLOCKS 128                 // 32 planes x 4 y-stripes
#define RB 2                        // ring slots; (slot, sign-parity) = epoch mod 4

// ws: u64 ring[RB][3][NCELL] SoA streams (stream k = channels 2k,2k+1), then
// int flags. Epoch tag = sign bits (phi in [0,1] post-clip -> sign always 0):
// producer ORs parity P=(e>>1)&1 into both sign bits; (slot=e&1, P) = e mod 4.
// Mutual neighbor dependency bounds skew<=1 -> 1-bit parity disambiguates
// (R9/R10-proven, absmax 0). Bootstrap-safe. Batched poll, tags post-checked.
//
// SESSION LEDGER (stepper us): R10 stripes 180.7 | R2 plane-blocks 247.7
// (coarse granularity FAILED) | R3 wave-blocks 190.0 (finer granularity
// NEUTRAL) | R4 k=2 batching 208 (radius-2 halo: 8 partners, FAILED).
// Model: per-step ~2.0us flat across geometry; floor arithmetic ~0.65us ->
// ~1.4us/step unexplained.
//
// R5 THEORY (per-hop RT reduction, R10 structure byte-identical otherwise):
// (a) SYSTEM->AGENT scope on all ring/flag atomics: device scope suffices for
//     GPU-internal cross-XCD coherence; system scope may pay extra.
// (b) nontemporal history stores: FETCH=43MB (~0.43MB/step) = ring poll loads
//     MISSING L3 to HBM (~900cy) because 135MB of history streaming evicts
//     ring lines. nt stores keep the 1.6MB ring L3-resident.
// Predict: stepper 130-160us, FETCH <20MB if real; null -> RT is intrinsic.
//
// R7 NOTE: R6 failed to COMPILE — __builtin_nontemporal_store rejects
// float4* (HIP_vector_type is a class, not a native vector). Fix: cast fill
// stores to native ext_vector_type(4) float. No semantic change; the R5
// experiment is otherwise byte-identical and still unmeasured.
#define RING_WORDS ((size_t)RB * 3 * NCELL)
#define F_DONE 0

typedef unsigned long long u64;
typedef float fx4 __attribute__((ext_vector_type(4)));   // native vec for nt store

__device__ __forceinline__ u64 ld64(const u64* p) {
    return __hip_atomic_load(p, __ATOMIC_RELAXED, __HIP_MEMORY_SCOPE_AGENT);
}
__device__ __forceinline__ void st64(u64* p, u64 v) {
    __hip_atomic_store(p, v, __ATOMIC_RELAXED, __HIP_MEMORY_SCOPE_AGENT);
}
__device__ __forceinline__ int ldi(const int* p) {
    return __hip_atomic_load(p, __ATOMIC_RELAXED, __HIP_MEMORY_SCOPE_AGENT);
}
__device__ __forceinline__ void sti(int* p, int v) {
    __hip_atomic_store(p, v, __ATOMIC_RELAXED, __HIP_MEMORY_SCOPE_AGENT);
}
__device__ __forceinline__ u64 pack2p(float a, float b, unsigned P) {
    const u64 w = ((u64)__float_as_uint(b) << 32) | __float_as_uint(a);
    return P ? (w | 0x8000000080000000ULL) : w;
}
__device__ __forceinline__ bool tagok(u64 w, unsigned P) {
    return (((unsigned)(w >> 63)) == P) & ((((unsigned)w) >> 31) == P);
}
__device__ __forceinline__ void unpack2(u64 w, float* d0, float* d1) {
    *d0 = __uint_as_float((unsigned)w & 0x7fffffffu);
    *d1 = __uint_as_float((unsigned)(w >> 32) & 0x7fffffffu);
}

__global__ void __launch_bounds__(NTHREADS)
BEMNA_V7_2_PhaseSpace_44117904064519_kernel(
    const float* __restrict__ D,
    const int* __restrict__ sx_p, const int* __restrict__ sy_p,
    const int* __restrict__ sz_p, const int* __restrict__ ex_p,
    const int* __restrict__ ey_p, const int* __restrict__ ez_p,
    const int* __restrict__ maxit_p,
    float* __restrict__ out,
    u64* __restrict__ ring,
    int* __restrict__ flags)
{
    __shared__ float tile[2][NCH][NTHREADS];   // ping-pong own stripe
    __shared__ int lds_dn;
    volatile int* vdn = &lds_dn;

    const int tid = (int)threadIdx.x;          // yl*32+z
    const int bx  = (int)blockIdx.x;
    const int x   = bx >> 2;                   // plane
    const int s   = bx & 3;                    // y-stripe
    const int yl  = tid >> 5;                  // 0..7
    const int z   = tid & 31;
    const int y   = (s << 3) + yl;
    const int cell = (x << 10) + (y << 5) + z;

    const int sx = *sx_p, sy = *sy_p, sz = *sz_p;
    const int ex = *ex_p, ey = *ey_p, ez = *ez_p;
    const int maxit = *maxit_p;
    const bool is_seed   = (cell == ((sx << 10) | (sy << 5) | sz));
    const bool is_target = (cell == ((ex << 10) | (ey << 5) | ez));

    // o=0 reads (x-1); o=1 (x+1); o=2 (y-1); o=3 (y+1); o=4 (z-1); o=5 (z+1)
    const int  nbg[NCH] = { cell - PLANE, cell + PLANE, cell - 32, cell + 32, cell - 1, cell + 1 };
    const bool ok[NCH]  = { x >= 1, x <= 30, y >= 1, y <= 30, z >= 1, z <= 30 };
    const int izm = (tid - 1) & (NTHREADS - 1), izp = (tid + 1) & (NTHREADS - 1);

    // halo groups this thread needs from the ring
    const bool has_xm = (x >= 1), has_xp = (x <= 30);
    const bool has_ym = (yl == 0) && (y >= 1);
    const bool has_yp = (yl == 7) && (y <= 30);

    // D step-invariant: 36 coefficients in registers (zeroed out-of-bounds)
    float dreg[NCH][NCH];
#pragma unroll
    for (int o = 0; o < NCH; ++o)
#pragma unroll
        for (int i = 0; i < NCH; ++i)
            dreg[o][i] = ok[o] ? D[(size_t)(o * NCH + i) * NCELL + nbg[o]] + 0.95f : 0.0f;

    // ---- init: epoch 0 (slot 0, parity 0 = plain), hist slice 0, tile[0] ----
    const float iv = is_seed ? 1.0f : 0.0f;
    {
        const u64 p = pack2p(iv, iv, 0);
        st64(&ring[0 * NCELL + cell], p);
        st64(&ring[1 * NCELL + cell], p);
        st64(&ring[2 * NCELL + cell], p);
        float* outp = out + cell;
#pragma unroll
        for (int o = 0; o < NCH; ++o) {
            __builtin_nontemporal_store(iv, outp + o * NCELL);
            tile[0][o][tid] = iv;
        }
    }
    if (tid == 0) lds_dn = -1;
    __syncthreads();                           // lds_dn + tile[0] visible

    int tripped = 0;
    // iteration t consumes epoch t, produces phi_{t+1} (= history slice t+1)
    for (int t = 0; t <= maxit - 2; ++t) {
        const u64* r0 = ring + (size_t)(t & 1) * 3 * NCELL;
        const u64* r1 = r0 + NCELL;
        const u64* r2 = r1 + NCELL;
        const unsigned P = (unsigned)((t >> 1) & 1);
        const int cm = cell - PLANE, cp = cell + PLANE;
        const int am = cell - 32,    ap = cell + 32;

        // zero-init so masked/boundary lanes never feed garbage (NaN x 0)
        u64 wa0 = 0, wa1 = 0, wa2 = 0, wb0 = 0, wb1 = 0, wb2 = 0;
        u64 wc0 = 0, wc1 = 0, wc2 = 0, wd0 = 0, wd1 = 0, wd2 = 0;
        for (;;) {
            // batched independent loads -> one waitcnt, one L3 RT per round
            if (has_xm) { wa0 = ld64(r0 + cm); wa1 = ld64(r1 + cm); wa2 = ld64(r2 + cm); }
            if (has_xp) { wb0 = ld64(r0 + cp); wb1 = ld64(r1 + cp); wb2 = ld64(r2 + cp); }
            if (has_ym) { wc0 = ld64(r0 + am); wc1 = ld64(r1 + am); wc2 = ld64(r2 + am); }
            if (has_yp) { wd0 = ld64(r0 + ap); wd1 = ld64(r1 + ap); wd2 = ld64(r2 + ap); }
            if ((tid & 63) == 0) {             // lane0/wave: done-flag duty
                const int dn = ldi(&flags[F_DONE]);
                if (dn >= 0) *vdn = dn;
            }
            // tag checks AFTER all loads are in flight
            bool okr = true;
            if (has_xm) okr = okr & tagok(wa0, P) & tagok(wa1, P) & tagok(wa2, P);
            if (has_xp) okr = okr & tagok(wb0, P) & tagok(wb1, P) & tagok(wb2, P);
            if (has_ym) okr = okr & tagok(wc0, P) & tagok(wc1, P) & tagok(wc2, P);
            if (has_yp) okr = okr & tagok(wd0, P) & tagok(wd1, P) & tagok(wd2, P);
            const int d = *vdn;                // LDS broadcast
            if (d >= 0 && t + 1 > d) break;    // abort: data moot
            if (__ballot(okr) == ~0ull) break;
            __builtin_amdgcn_s_sleep(1);
        }
        __syncthreads();                       // tile writes settled block-wide
        { const int d = *vdn; if (d >= 0 && t + 1 > d) break; }  // uniform abort

        float xm[NCH], xp[NCH], ym[NCH], yp[NCH];
        unpack2(wa0, &xm[0], &xm[1]); unpack2(wa1, &xm[2], &xm[3]); unpack2(wa2, &xm[4], &xm[5]);
        unpack2(wb0, &xp[0], &xp[1]); unpack2(wb1, &xp[2], &xp[3]); unpack2(wb2, &xp[4], &xp[5]);
        unpack2(wc0, &ym[0], &ym[1]); unpack2(wc1, &ym[2], &ym[3]); unpack2(wc2, &ym[4], &ym[5]);
        unpack2(wd0, &yp[0], &yp[1]); unpack2(wd1, &yp[2], &yp[3]); unpack2(wd2, &yp[4], &yp[5]);

        // in-stripe y neighbors from LDS (dreg masks y==0/31 edges)
        const float (*L)[NTHREADS] = tile[t & 1];
        if (!has_ym) {
            const int n = (tid - 32) & (NTHREADS - 1);
#pragma unroll
            for (int i = 0; i < NCH; ++i) ym[i] = L[i][n];
        }
        if (!has_yp) {
            const int n = (tid + 32) & (NTHREADS - 1);
#pragma unroll
            for (int i = 0; i < NCH; ++i) yp[i] = L[i][n];
        }

        float v[NCH];
        {
            float a0 = 0.f, a1 = 0.f, a2 = 0.f, a3 = 0.f, a4 = 0.f, a5 = 0.f;
#pragma unroll
            for (int i = 0; i < NCH; ++i) {
                a0 = fmaf(dreg[0][i], xm[i], a0);
                a1 = fmaf(dreg[1][i], xp[i], a1);
                a2 = fmaf(dreg[2][i], ym[i], a2);
                a3 = fmaf(dreg[3][i], yp[i], a3);
                a4 = fmaf(dreg[4][i], L[i][izm], a4);
                a5 = fmaf(dreg[5][i], L[i][izp], a5);
            }
            v[0] = fminf(fmaxf(a0, 0.f), 1.f);
            v[1] = fminf(fmaxf(a1, 0.f), 1.f);
            v[2] = fminf(fmaxf(a2, 0.f), 1.f);
            v[3] = fminf(fmaxf(a3, 0.f), 1.f);
            v[4] = fminf(fmaxf(a4, 0.f), 1.f);
            v[5] = fminf(fmaxf(a5, 0.f), 1.f);
        }

        // trip: phi_{t+1} is the frozen state -> done_step = t+1
        if (is_target && !tripped) {
            if (v[0] + v[1] + v[2] + v[3] + v[4] + v[5] > 0.01f) {
                sti(&flags[F_DONE], t + 1);
                tripped = 1;
            }
        }

        // publish epoch t+1: fire-and-forget tagged stores (no drain, no flag)
        {
            const unsigned P1 = (unsigned)(((t + 1) >> 1) & 1);
            u64* w0 = ring + (size_t)((t + 1) & 1) * 3 * NCELL;
            st64(w0 + 0 * NCELL + cell, pack2p(v[0], v[1], P1));
            st64(w0 + 1 * NCELL + cell, pack2p(v[2], v[3], P1));
            st64(w0 + 2 * NCELL + cell, pack2p(v[4], v[5], P1));
#pragma unroll
            for (int o = 0; o < NCH; ++o) tile[(t + 1) & 1][o][tid] = v[o];
        }

        // history slice t+1 last, NON-TEMPORAL: don't evict ring from L3
        {
            float* outp = out + (size_t)(t + 1) * STEP_STRIDE + cell;
#pragma unroll
            for (int o = 0; o < NCH; ++o)
                __builtin_nontemporal_store(v[o], outp + o * NCELL);
        }
    }
}

// Read-once/write-many fill: one 16B lane per slice element. Each thread
// loads its element of the frozen slice out[tf] ONCE and streams it to
// slices tf+1..maxit-1 (contiguous 4KB bursts per block per slice),
// overwriting any stepper overshoot. nt stores via native ext_vector_type
// (HIP float4 is a class type the builtin rejects).
__global__ void fill_kernel(const int* __restrict__ flags,
                            float* __restrict__ outf,
                            int total4)
{
    const int s4 = STEP_STRIDE / 4;
    const int maxit = total4 / s4;
    const int ds = flags[F_DONE];
    const int tf = (ds >= 1 && ds <= maxit - 1) ? ds : maxit - 1;
    const int idx = (int)blockIdx.x * (int)blockDim.x + (int)threadIdx.x;
    fx4* o4 = (fx4*)outf;
    const fx4 v = o4[(size_t)tf * s4 + idx];
    for (int t = tf + 1; t < maxit; ++t)
        __builtin_nontemporal_store(v, &o4[(size_t)t * s4 + idx]);
}

extern "C" void kernel_launch(void* const* d_in, const int* in_sizes, int n_in,
                              void* d_out, int out_size, void* d_ws, size_t ws_size,
                              hipStream_t stream)
{
    const float* D   = (const float*)d_in[0];
    const int* sx    = (const int*)d_in[1];
    const int* sy    = (const int*)d_in[2];
    const int* sz    = (const int*)d_in[3];
    const int* ex    = (const int*)d_in[4];
    const int* ey    = (const int*)d_in[5];
    const int* ez    = (const int*)d_in[6];
    const int* maxit = (const int*)d_in[7];
    float* out = (float*)d_out;

    u64* ring  = (u64*)d_ws;                   // 2 x 3 x 32768 x 8B = 1.6 MB
    int* flags = (int*)(ring + RING_WORDS);

    // 128 blocks x 256 threads (x-plane x y-stripe); plain launch, tagged
    // dataflow sync. Co-residency by capacity (128 blocks << 256 CUs).
    BEMNA_V7_2_PhaseSpace_44117904064519_kernel<<<dim3(NBLOCKS), dim3(NTHREADS), 0, stream>>>(
        D, sx, sy, sz, ex, ey, ez, maxit, out, ring, flags);

    // one 16B lane per slice element: STEP_STRIDE/4 = 49152 threads
    const int total4 = out_size / 4;
    fill_kernel<<<dim3((STEP_STRIDE / 4) / 256), dim3(256), 0, stream>>>(
        flags, out, total4);
}

// Round 9
// 401.946 us; speedup vs baseline: 1.0644x; 1.0256x over previous
//
#include <hip/hip_runtime.h>

#define NCH 6
#define NX 32
#define PLANE 1024                  // 32x32 cells per x-plane
#define NCELL (NX * PLANE)
#define STEP_STRIDE (NCH * NCELL)   // floats per history slice
#define NTHREADS 256                // one y-stripe (8 rows x 32 z) of a plane
#define NBLOCKS 128                 // 32 planes x 4 y-stripes
#define RB 2                        // ring slots; (slot, sign-parity) = epoch mod 4

// ws: u64 ring[RB][3][NCELL] SoA streams (stream k = channels 2k,2k+1), then
// int flags. Epoch tag = sign bits (phi in [0,1] post-clip -> sign always 0):
// producer ORs parity P=(e>>1)&1 into both sign bits; (slot=e&1, P) = e mod 4.
// Mutual neighbor dependency bounds skew<=1 -> 1-bit parity disambiguates
// (R9/R10-proven, absmax 0). Bootstrap-safe. Batched poll, tags post-checked.
//
// SESSION LEDGER (stepper us): R10 stripes 180.7 | R2 plane-blocks 247.7
// (coarse FAILED) | R3 wave-blocks 190.0 (finer NEUTRAL) | R4 k=2 batching
// 208 (8 partners FAILED) | R5 agent-scope + nt-stores 182.3 (NULL both:
// scope is free, FETCH unchanged -> poll misses not L3-eviction).
// MODEL: per-step ~2.0us invariant across geometry/partners/batching/scope/
// L3 -> intrinsic cross-XCD store->visibility->load chain; steady-state
// period of a mutual-dependency graph = slowest edge cost (swizzle can't
// help: boundary edges gate every step).
//
// R8 (final micro-package, protocol untouched):
// (a) done-flag joins the batched poll for ALL lanes (broadcast load) ->
//     removes lane0->LDS-volatile->read chain (~50-100cy) from every poll
//     round; post-loop uniform abort via plain LDS + existing barrier.
// (b) no sleep on first retry (saves 64cy on the common 1-retry path).
// Predict stepper 170-177. If delta < 5us -> floor confirmed: 88 inherent
// sequential steps x ~2us fabric handshake + ~30us fill + ~190us fixed
// harness envelope ~= 400us total; declare ROOFLINE next round.
#define RING_WORDS ((size_t)RB * 3 * NCELL)
#define F_DONE 0

typedef unsigned long long u64;
typedef float fx4 __attribute__((ext_vector_type(4)));   // native vec for nt store

__device__ __forceinline__ u64 ld64(const u64* p) {
    return __hip_atomic_load(p, __ATOMIC_RELAXED, __HIP_MEMORY_SCOPE_AGENT);
}
__device__ __forceinline__ void st64(u64* p, u64 v) {
    __hip_atomic_store(p, v, __ATOMIC_RELAXED, __HIP_MEMORY_SCOPE_AGENT);
}
__device__ __forceinline__ int ldi(const int* p) {
    return __hip_atomic_load(p, __ATOMIC_RELAXED, __HIP_MEMORY_SCOPE_AGENT);
}
__device__ __forceinline__ void sti(int* p, int v) {
    __hip_atomic_store(p, v, __ATOMIC_RELAXED, __HIP_MEMORY_SCOPE_AGENT);
}
__device__ __forceinline__ u64 pack2p(float a, float b, unsigned P) {
    const u64 w = ((u64)__float_as_uint(b) << 32) | __float_as_uint(a);
    return P ? (w | 0x8000000080000000ULL) : w;
}
__device__ __forceinline__ bool tagok(u64 w, unsigned P) {
    return (((unsigned)(w >> 63)) == P) & ((((unsigned)w) >> 31) == P);
}
__device__ __forceinline__ void unpack2(u64 w, float* d0, float* d1) {
    *d0 = __uint_as_float((unsigned)w & 0x7fffffffu);
    *d1 = __uint_as_float((unsigned)(w >> 32) & 0x7fffffffu);
}

__global__ void __launch_bounds__(NTHREADS)
BEMNA_V7_2_PhaseSpace_44117904064519_kernel(
    const float* __restrict__ D,
    const int* __restrict__ sx_p, const int* __restrict__ sy_p,
    const int* __restrict__ sz_p, const int* __restrict__ ex_p,
    const int* __restrict__ ey_p, const int* __restrict__ ez_p,
    const int* __restrict__ maxit_p,
    float* __restrict__ out,
    u64* __restrict__ ring,
    int* __restrict__ flags)
{
    __shared__ float tile[2][NCH][NTHREADS];   // ping-pong own stripe
    __shared__ int lds_dn;                     // post-loop uniform abort relay

    const int tid = (int)threadIdx.x;          // yl*32+z
    const int bx  = (int)blockIdx.x;
    const int x   = bx >> 2;                   // plane
    const int s   = bx & 3;                    // y-stripe
    const int yl  = tid >> 5;                  // 0..7
    const int z   = tid & 31;
    const int y   = (s << 3) + yl;
    const int cell = (x << 10) + (y << 5) + z;

    const int sx = *sx_p, sy = *sy_p, sz = *sz_p;
    const int ex = *ex_p, ey = *ey_p, ez = *ez_p;
    const int maxit = *maxit_p;
    const bool is_seed   = (cell == ((sx << 10) | (sy << 5) | sz));
    const bool is_target = (cell == ((ex << 10) | (ey << 5) | ez));

    // o=0 reads (x-1); o=1 (x+1); o=2 (y-1); o=3 (y+1); o=4 (z-1); o=5 (z+1)
    const int  nbg[NCH] = { cell - PLANE, cell + PLANE, cell - 32, cell + 32, cell - 1, cell + 1 };
    const bool ok[NCH]  = { x >= 1, x <= 30, y >= 1, y <= 30, z >= 1, z <= 30 };
    const int izm = (tid - 1) & (NTHREADS - 1), izp = (tid + 1) & (NTHREADS - 1);

    // halo groups this thread needs from the ring
    const bool has_xm = (x >= 1), has_xp = (x <= 30);
    const bool has_ym = (yl == 0) && (y >= 1);
    const bool has_yp = (yl == 7) && (y <= 30);

    // D step-invariant: 36 coefficients in registers (zeroed out-of-bounds)
    float dreg[NCH][NCH];
#pragma unroll
    for (int o = 0; o < NCH; ++o)
#pragma unroll
        for (int i = 0; i < NCH; ++i)
            dreg[o][i] = ok[o] ? D[(size_t)(o * NCH + i) * NCELL + nbg[o]] + 0.95f : 0.0f;

    // ---- init: epoch 0 (slot 0, parity 0 = plain), hist slice 0, tile[0] ----
    const float iv = is_seed ? 1.0f : 0.0f;
    {
        const u64 p = pack2p(iv, iv, 0);
        st64(&ring[0 * NCELL + cell], p);
        st64(&ring[1 * NCELL + cell], p);
        st64(&ring[2 * NCELL + cell], p);
        float* outp = out + cell;
#pragma unroll
        for (int o = 0; o < NCH; ++o) {
            __builtin_nontemporal_store(iv, outp + o * NCELL);
            tile[0][o][tid] = iv;
        }
    }
    __syncthreads();                           // tile[0] visible

    int tripped = 0;
    // iteration t consumes epoch t, produces phi_{t+1} (= history slice t+1)
    for (int t = 0; t <= maxit - 2; ++t) {
        const u64* r0 = ring + (size_t)(t & 1) * 3 * NCELL;
        const u64* r1 = r0 + NCELL;
        const u64* r2 = r1 + NCELL;
        const unsigned P = (unsigned)((t >> 1) & 1);
        const int cm = cell - PLANE, cp = cell + PLANE;
        const int am = cell - 32,    ap = cell + 32;

        // zero-init so masked/boundary lanes never feed garbage (NaN x 0)
        u64 wa0 = 0, wa1 = 0, wa2 = 0, wb0 = 0, wb1 = 0, wb2 = 0;
        u64 wc0 = 0, wc1 = 0, wc2 = 0, wd0 = 0, wd1 = 0, wd2 = 0;
        int dn = -1, spins = 0;
        for (;;) {
            // batched independent loads -> one waitcnt, one L3 RT per round.
            // done-flag load joins the batch for ALL lanes (same address =
            // broadcast): wave-uniform register, no LDS relay in the loop.
            if (has_xm) { wa0 = ld64(r0 + cm); wa1 = ld64(r1 + cm); wa2 = ld64(r2 + cm); }
            if (has_xp) { wb0 = ld64(r0 + cp); wb1 = ld64(r1 + cp); wb2 = ld64(r2 + cp); }
            if (has_ym) { wc0 = ld64(r0 + am); wc1 = ld64(r1 + am); wc2 = ld64(r2 + am); }
            if (has_yp) { wd0 = ld64(r0 + ap); wd1 = ld64(r1 + ap); wd2 = ld64(r2 + ap); }
            dn = ldi(&flags[F_DONE]);
            // tag checks AFTER all loads are in flight
            bool okr = true;
            if (has_xm) okr = okr & tagok(wa0, P) & tagok(wa1, P) & tagok(wa2, P);
            if (has_xp) okr = okr & tagok(wb0, P) & tagok(wb1, P) & tagok(wb2, P);
            if (has_ym) okr = okr & tagok(wc0, P) & tagok(wc1, P) & tagok(wc2, P);
            if (has_yp) okr = okr & tagok(wd0, P) & tagok(wd1, P) & tagok(wd2, P);
            if (dn >= 0 && t + 1 > dn) break;  // abort: data moot (wave-uniform)
            if (__ballot(okr) == ~0ull) break;
            if (spins++) __builtin_amdgcn_s_sleep(1);   // no sleep on 1st retry
        }
        if (tid == 0) lds_dn = dn;             // relay wave0's flag sample
        __syncthreads();                       // tile writes settled + lds_dn
        if (lds_dn >= 0 && t + 1 > lds_dn) break;   // block-uniform abort

        float xm[NCH], xp[NCH], ym[NCH], yp[NCH];
        unpack2(wa0, &xm[0], &xm[1]); unpack2(wa1, &xm[2], &xm[3]); unpack2(wa2, &xm[4], &xm[5]);
        unpack2(wb0, &xp[0], &xp[1]); unpack2(wb1, &xp[2], &xp[3]); unpack2(wb2, &xp[4], &xp[5]);
        unpack2(wc0, &ym[0], &ym[1]); unpack2(wc1, &ym[2], &ym[3]); unpack2(wc2, &ym[4], &ym[5]);
        unpack2(wd0, &yp[0], &yp[1]); unpack2(wd1, &yp[2], &yp[3]); unpack2(wd2, &yp[4], &yp[5]);

        // in-stripe y neighbors from LDS (dreg masks y==0/31 edges)
        const float (*L)[NTHREADS] = tile[t & 1];
        if (!has_ym) {
            const int n = (tid - 32) & (NTHREADS - 1);
#pragma unroll
            for (int i = 0; i < NCH; ++i) ym[i] = L[i][n];
        }
        if (!has_yp) {
            const int n = (tid + 32) & (NTHREADS - 1);
#pragma unroll
            for (int i = 0; i < NCH; ++i) yp[i] = L[i][n];
        }

        float v[NCH];
        {
            float a0 = 0.f, a1 = 0.f, a2 = 0.f, a3 = 0.f, a4 = 0.f, a5 = 0.f;
#pragma unroll
            for (int i = 0; i < NCH; ++i) {
                a0 = fmaf(dreg[0][i], xm[i], a0);
                a1 = fmaf(dreg[1][i], xp[i], a1);
                a2 = fmaf(dreg[2][i], ym[i], a2);
                a3 = fmaf(dreg[3][i], yp[i], a3);
                a4 = fmaf(dreg[4][i], L[i][izm], a4);
                a5 = fmaf(dreg[5][i], L[i][izp], a5);
            }
            v[0] = fminf(fmaxf(a0, 0.f), 1.f);
            v[1] = fminf(fmaxf(a1, 0.f), 1.f);
            v[2] = fminf(fmaxf(a2, 0.f), 1.f);
            v[3] = fminf(fmaxf(a3, 0.f), 1.f);
            v[4] = fminf(fmaxf(a4, 0.f), 1.f);
            v[5] = fminf(fmaxf(a5, 0.f), 1.f);
        }

        // trip: phi_{t+1} is the frozen state -> done_step = t+1
        if (is_target && !tripped) {
            if (v[0] + v[1] + v[2] + v[3] + v[4] + v[5] > 0.01f) {
                sti(&flags[F_DONE], t + 1);
                tripped = 1;
            }
        }

        // publish epoch t+1: fire-and-forget tagged stores (no drain, no flag)
        {
            const unsigned P1 = (unsigned)(((t + 1) >> 1) & 1);
            u64* w0 = ring + (size_t)((t + 1) & 1) * 3 * NCELL;
            st64(w0 + 0 * NCELL + cell, pack2p(v[0], v[1], P1));
            st64(w0 + 1 * NCELL + cell, pack2p(v[2], v[3], P1));
            st64(w0 + 2 * NCELL + cell, pack2p(v[4], v[5], P1));
#pragma unroll
            for (int o = 0; o < NCH; ++o) tile[(t + 1) & 1][o][tid] = v[o];
        }

        // history slice t+1 last, NON-TEMPORAL (neutral but harmless): the
        // HBM acks overlap the next poll
        {
            float* outp = out + (size_t)(t + 1) * STEP_STRIDE + cell;
#pragma unroll
            for (int o = 0; o < NCH; ++o)
                __builtin_nontemporal_store(v[o], outp + o * NCELL);
        }
    }
}

// Read-once/write-many fill: one 16B lane per slice element. Each thread
// loads its element of the frozen slice out[tf] ONCE and streams it to
// slices tf+1..maxit-1 (contiguous 4KB bursts per block per slice),
// overwriting any stepper overshoot. nt stores via native ext_vector_type
// (HIP float4 is a class type the builtin rejects).
__global__ void fill_kernel(const int* __restrict__ flags,
                            float* __restrict__ outf,
                            int total4)
{
    const int s4 = STEP_STRIDE / 4;
    const int maxit = total4 / s4;
    const int ds = flags[F_DONE];
    const int tf = (ds >= 1 && ds <= maxit - 1) ? ds : maxit - 1;
    const int idx = (int)blockIdx.x * (int)blockDim.x + (int)threadIdx.x;
    fx4* o4 = (fx4*)outf;
    const fx4 v = o4[(size_t)tf * s4 + idx];
    for (int t = tf + 1; t < maxit; ++t)
        __builtin_nontemporal_store(v, &o4[(size_t)t * s4 + idx]);
}

extern "C" void kernel_launch(void* const* d_in, const int* in_sizes, int n_in,
                              void* d_out, int out_size, void* d_ws, size_t ws_size,
                              hipStream_t stream)
{
    const float* D   = (const float*)d_in[0];
    const int* sx    = (const int*)d_in[1];
    const int* sy    = (const int*)d_in[2];
    const int* sz    = (const int*)d_in[3];
    const int* ex    = (const int*)d_in[4];
    const int* ey    = (const int*)d_in[5];
    const int* ez    = (const int*)d_in[6];
    const int* maxit = (const int*)d_in[7];
    float* out = (float*)d_out;

    u64* ring  = (u64*)d_ws;                   // 2 x 3 x 32768 x 8B = 1.6 MB
    int* flags = (int*)(ring + RING_WORDS);

    // 128 blocks x 256 threads (x-plane x y-stripe); plain launch, tagged
    // dataflow sync. Co-residency by capacity (128 blocks << 256 CUs).
    BEMNA_V7_2_PhaseSpace_44117904064519_kernel<<<dim3(NBLOCKS), dim3(NTHREADS), 0, stream>>>(
        D, sx, sy, sz, ex, ey, ez, maxit, out, ring, flags);

    // one 16B lane per slice element: STEP_STRIDE/4 = 49152 threads
    const int total4 = out_size / 4;
    fill_kernel<<<dim3((STEP_STRIDE / 4) / 256), dim3(256), 0, stream>>>(
        flags, out, total4);
}

// Round 10
// 347.629 us; speedup vs baseline: 1.2307x; 1.1563x over previous
//
#include <hip/hip_runtime.h>

#define NCH 6
#define NX 32
#define PLANE 1024                  // 32x32 cells per x-plane
#define NCELL (NX * PLANE)
#define STEP_STRIDE (NCH * NCELL)   // floats per history slice
#define NTHREADS 256                // one y-stripe (8 rows x 32 z) of a plane
#define NBLOCKS 128                 // 32 planes x 4 y-stripes
#define RB 2                        // ring slots; (slot, sign-parity) = epoch mod 4

// R9: DIRECTED-VALUE (scatter-form) PROTOCOL. The consumer of a face never
// needs the neighbor's 6-ch phi — only the scalar phi_out[o](neighbor), and
// the producer can compute it from ITS OWN D and phi:
//   v[o](cell) = clip( phi_out[o](face-neighbor) ),
//   phi_out[o](c) = sum_i (D[o,i,c]+0.95) * phi[i,c].
// So the 36-FMA moves producer-side (own-cell D, no halo needed for compute)
// and the ring payload shrinks: poll 6x u64 -> 2x u32 interior (3 at stripe
// edges); publish 3x u64 -> 2-3x u32; y-interior via 2 LDS floats (was 6);
// z-exchange via in-register __shfl (width 32 = one row). Arithmetic is
// bitwise-identical to R10's gather form (same fmaf chains) -> absmax 0.
// Tag = sign bit (phi_out >= 0 always); slot=epoch&1, parity=(epoch>>1)&1;
// mutual-partner skew<=1 proof unchanged; poison 0xAA sign=1 tag-fails ->
// bootstrap waits for init stores (R8-proven behavior preserved).
//
// SESSION LEDGER (stepper us): R10 stripes 180.7 | R2 plane-blocks 247.7 F |
// R3 wave-blocks 190.0 N | R4 k=2 batch 208 F | R5 scope+nt 182.3 NULL |
// R8 poll-slim 171.6 WIN (flag-in-batch + no-1st-sleep; predicted 170-177).
// R8 proved poll-round contents are the live lever (~100cy/round ~ 10us).
// R9 predict: stepper 140-160, FETCH 43->10-18MB, WRITE ~95-105MB, absmax 0.
// If >165 -> pure fabric latency; declare roofline with arithmetic.
#define RING32_WORDS ((size_t)RB * 4 * NCELL)   // u32 words: slot x dir x cell
#define F_DONE 0

typedef unsigned long long u64;
typedef unsigned int u32;
typedef float fx4 __attribute__((ext_vector_type(4)));   // native vec for nt store

__device__ __forceinline__ u32 ld32(const u32* p) {
    return __hip_atomic_load(p, __ATOMIC_RELAXED, __HIP_MEMORY_SCOPE_AGENT);
}
__device__ __forceinline__ void st32(u32* p, u32 v) {
    __hip_atomic_store(p, v, __ATOMIC_RELAXED, __HIP_MEMORY_SCOPE_AGENT);
}
__device__ __forceinline__ int ldi(const int* p) {
    return __hip_atomic_load(p, __ATOMIC_RELAXED, __HIP_MEMORY_SCOPE_AGENT);
}
__device__ __forceinline__ void sti(int* p, int v) {
    __hip_atomic_store(p, v, __ATOMIC_RELAXED, __HIP_MEMORY_SCOPE_AGENT);
}
__device__ __forceinline__ u32 tagf(float a, unsigned P) {
    const u32 w = __float_as_uint(a);            // phi_out >= 0 -> sign free
    return P ? (w | 0x80000000u) : w;
}
__device__ __forceinline__ float untagf(u32 w) {
    return __uint_as_float(w & 0x7fffffffu);
}

__global__ void __launch_bounds__(NTHREADS)
BEMNA_V7_2_PhaseSpace_44117904064519_kernel(
    const float* __restrict__ D,
    const int* __restrict__ sx_p, const int* __restrict__ sy_p,
    const int* __restrict__ sz_p, const int* __restrict__ ex_p,
    const int* __restrict__ ey_p, const int* __restrict__ ez_p,
    const int* __restrict__ maxit_p,
    float* __restrict__ out,
    u32* __restrict__ ring,
    int* __restrict__ flags)
{
    __shared__ float tile[2][2][NTHREADS];     // ping-pong: [buf][dir2/dir3][tid]
    __shared__ int lds_dn;                     // post-loop uniform abort relay

    const int tid = (int)threadIdx.x;          // yl*32+z
    const int bx  = (int)blockIdx.x;
    const int x   = bx >> 2;                   // plane
    const int s   = bx & 3;                    // y-stripe
    const int yl  = tid >> 5;                  // 0..7
    const int z   = tid & 31;
    const int y   = (s << 3) + yl;
    const int cell = (x << 10) + (y << 5) + z;

    const int sx = *sx_p, sy = *sy_p, sz = *sz_p;
    const int ex = *ex_p, ey = *ey_p, ez = *ez_p;
    const int maxit = *maxit_p;
    const bool is_seed   = (cell == ((sx << 10) | (sy << 5) | sz));
    const bool is_target = (cell == ((ex << 10) | (ey << 5) | ez));

    // D at OWN cell (scatter form): always in-bounds, no masking needed.
    float dreg[NCH][NCH];
#pragma unroll
    for (int o = 0; o < NCH; ++o)
#pragma unroll
        for (int i = 0; i < NCH; ++i)
            dreg[o][i] = D[(size_t)(o * NCH + i) * NCELL + cell] + 0.95f;

    // ring roles: dir0 read by x+1 | dir1 by x-1 | dir2 by y+1 (stripe above)
    // | dir3 by y-1 (stripe below). Boundary masking at ASSEMBLY (v=0).
    const bool has_xm  = (x >= 1), has_xp = (x <= 30);
    const bool edge_ym = (yl == 0), edge_yp = (yl == 7);
    const bool has_ym  = edge_ym && (y >= 1);   // poll dir2 @ cell-32
    const bool has_yp  = edge_yp && (y <= 30);  // poll dir3 @ cell+32
    const bool pub_d2  = edge_yp && (y <= 30);  // my dir2 read by stripe above
    const bool pub_d3  = edge_ym && (y >= 1);   // my dir3 read by stripe below

    // ---- init: epoch 0 (slot 0, parity 0), hist slice 0 ----
    const float iv = is_seed ? 1.0f : 0.0f;
    float pz4, pz5;                            // own z-dir values (in-register)
    {
        float po[NCH];
#pragma unroll
        for (int o = 0; o < NCH; ++o) {        // phi_0 = iv on ALL channels
            float a = 0.f;
#pragma unroll
            for (int i = 0; i < NCH; ++i) a = fmaf(dreg[o][i], iv, a);
            po[o] = a;
        }
        st32(ring + 0 * NCELL + cell, tagf(po[0], 0));
        st32(ring + 1 * NCELL + cell, tagf(po[1], 0));
        if (pub_d2) st32(ring + 2 * NCELL + cell, tagf(po[2], 0));
        if (pub_d3) st32(ring + 3 * NCELL + cell, tagf(po[3], 0));
        tile[0][0][tid] = po[2];
        tile[0][1][tid] = po[3];
        pz4 = po[4]; pz5 = po[5];
        float* outp = out + cell;
#pragma unroll
        for (int o = 0; o < NCH; ++o)
            __builtin_nontemporal_store(iv, outp + o * NCELL);
    }
    __syncthreads();                           // tile[0] visible

    int tripped = 0;
    // iteration t consumes epoch-t directed values, produces phi_{t+1}
    for (int t = 0; t <= maxit - 2; ++t) {
        const u32* r = ring + (size_t)(t & 1) * 4 * NCELL;
        const unsigned P = (unsigned)((t >> 1) & 1);

        u32 wxm = 0, wxp = 0, wym = 0, wyp = 0;
        int dn = -1, spins = 0;
        for (;;) {
            // batched poll: 2-3 u32 + flag -> one waitcnt, one L3 RT
            if (has_xm) wxm = ld32(r + 0 * NCELL + cell - PLANE);
            if (has_xp) wxp = ld32(r + 1 * NCELL + cell + PLANE);
            if (has_ym) wym = ld32(r + 2 * NCELL + cell - 32);
            if (has_yp) wyp = ld32(r + 3 * NCELL + cell + 32);
            dn = ldi(&flags[F_DONE]);          // same addr all lanes: broadcast
            bool okr = true;
            if (has_xm) okr = okr & ((wxm >> 31) == P);
            if (has_xp) okr = okr & ((wxp >> 31) == P);
            if (has_ym) okr = okr & ((wym >> 31) == P);
            if (has_yp) okr = okr & ((wyp >> 31) == P);
            if (dn >= 0 && t + 1 > dn) break;  // abort: data moot (wave-uniform)
            if (__ballot(okr) == ~0ull) break;
            if (spins++) __builtin_amdgcn_s_sleep(1);   // no sleep on 1st retry
        }
        if (tid == 0) lds_dn = dn;             // relay wave0's flag sample
        __syncthreads();                       // tile writes settled + lds_dn
        if (lds_dn >= 0 && t + 1 > lds_dn) break;   // block-uniform abort

        // ---- assemble phi_{t+1}: v[o] = clip(directed value from face o) ----
        float v[NCH];
        v[0] = has_xm ? untagf(wxm) : 0.0f;
        v[1] = has_xp ? untagf(wxp) : 0.0f;
        v[2] = edge_ym ? (has_ym ? untagf(wym) : 0.0f) : tile[t & 1][0][tid - 32];
        v[3] = edge_yp ? (has_yp ? untagf(wyp) : 0.0f) : tile[t & 1][1][tid + 32];
        const float s4 = __shfl_up(pz4, 1, 32);     // from z-1 (row = 32 lanes)
        const float s5 = __shfl_down(pz5, 1, 32);   // from z+1
        v[4] = (z >= 1)  ? s4 : 0.0f;
        v[5] = (z <= 30) ? s5 : 0.0f;
#pragma unroll
        for (int o = 0; o < NCH; ++o) v[o] = fminf(fmaxf(v[o], 0.0f), 1.0f);

        // trip: phi_{t+1} is the frozen state -> done_step = t+1
        if (is_target && !tripped) {
            if (v[0] + v[1] + v[2] + v[3] + v[4] + v[5] > 0.01f) {
                sti(&flags[F_DONE], t + 1);
                tripped = 1;
            }
        }

        // ---- produce directed values for epoch t+1 (own-cell D, 36 FMA) ----
        float n0 = 0.f, n1 = 0.f, n2 = 0.f, n3 = 0.f, n4 = 0.f, n5 = 0.f;
#pragma unroll
        for (int i = 0; i < NCH; ++i) {
            n0 = fmaf(dreg[0][i], v[i], n0);
            n1 = fmaf(dreg[1][i], v[i], n1);
            n2 = fmaf(dreg[2][i], v[i], n2);
            n3 = fmaf(dreg[3][i], v[i], n3);
            n4 = fmaf(dreg[4][i], v[i], n4);
            n5 = fmaf(dreg[5][i], v[i], n5);
        }

        // publish epoch t+1: fire-and-forget tagged u32 stores
        {
            const unsigned P1 = (unsigned)(((t + 1) >> 1) & 1);
            u32* w = ring + (size_t)((t + 1) & 1) * 4 * NCELL;
            st32(w + 0 * NCELL + cell, tagf(n0, P1));
            st32(w + 1 * NCELL + cell, tagf(n1, P1));
            if (pub_d2) st32(w + 2 * NCELL + cell, tagf(n2, P1));
            if (pub_d3) st32(w + 3 * NCELL + cell, tagf(n3, P1));
            tile[(t + 1) & 1][0][tid] = n2;
            tile[(t + 1) & 1][1][tid] = n3;
            pz4 = n4; pz5 = n5;
        }

        // history slice t+1 last, non-temporal: HBM acks overlap next poll
        {
            float* outp = out + (size_t)(t + 1) * STEP_STRIDE + cell;
#pragma unroll
            for (int o = 0; o < NCH; ++o)
                __builtin_nontemporal_store(v[o], outp + o * NCELL);
        }
    }
}

// Read-once/write-many fill: one 16B lane per slice element. Each thread
// loads its element of the frozen slice out[tf] ONCE and streams it to
// slices tf+1..maxit-1, overwriting any stepper overshoot. nt stores via
// native ext_vector_type (HIP float4 is a class the builtin rejects).
__global__ void fill_kernel(const int* __restrict__ flags,
                            float* __restrict__ outf,
                            int total4)
{
    const int s4 = STEP_STRIDE / 4;
    const int maxit = total4 / s4;
    const int ds = flags[F_DONE];
    const int tf = (ds >= 1 && ds <= maxit - 1) ? ds : maxit - 1;
    const int idx = (int)blockIdx.x * (int)blockDim.x + (int)threadIdx.x;
    fx4* o4 = (fx4*)outf;
    const fx4 v = o4[(size_t)tf * s4 + idx];
    for (int t = tf + 1; t < maxit; ++t)
        __builtin_nontemporal_store(v, &o4[(size_t)t * s4 + idx]);
}

extern "C" void kernel_launch(void* const* d_in, const int* in_sizes, int n_in,
                              void* d_out, int out_size, void* d_ws, size_t ws_size,
                              hipStream_t stream)
{
    const float* D   = (const float*)d_in[0];
    const int* sx    = (const int*)d_in[1];
    const int* sy    = (const int*)d_in[2];
    const int* sz    = (const int*)d_in[3];
    const int* ex    = (const int*)d_in[4];
    const int* ey    = (const int*)d_in[5];
    const int* ez    = (const int*)d_in[6];
    const int* maxit = (const int*)d_in[7];
    float* out = (float*)d_out;

    u32* ring  = (u32*)d_ws;                   // 2 x 4 x 32768 x 4B = 1.0 MB
    int* flags = (int*)(ring + RING32_WORDS);

    // 128 blocks x 256 threads (x-plane x y-stripe); plain launch, tagged
    // dataflow sync. Co-residency by capacity (128 blocks << 256 CUs).
    BEMNA_V7_2_PhaseSpace_44117904064519_kernel<<<dim3(NBLOCKS), dim3(NTHREADS), 0, stream>>>(
        D, sx, sy, sz, ex, ey, ez, maxit, out, ring, flags);

    // one 16B lane per slice element: STEP_STRIDE/4 = 49152 threads
    const int total4 = out_size / 4;
    fill_kernel<<<dim3((STEP_STRIDE / 4) / 256), dim3(256), 0, stream>>>(
        flags, out, total4);
}